// Round 11
// baseline (417.795 us; speedup 1.0000x reference)
//
#include <hip/hip_runtime.h>
#include <hip/hip_bf16.h>

// RGCN 2-layer + global mean pool + log_softmax. Round 11 (R10 compile fix).
// R9 + fused-gather MLP boost: each lane walks FOUR independent CSR segments
// (2 relations x 2 nodes, pairs (2p,2p+1)) as interleaved chains -> ~1.8x
// fewer serial epochs, 4 gathers in flight. Two per-wave A-tiles, MFMA
// consumes both per pair. Everything else unchanged from R9.

#define CH 64
#define BK_EDGES 2048
#define CAP 12288   // per-bucket record capacity (avg ~8163, >40 sigma)

typedef __attribute__((ext_vector_type(8))) short short8;
typedef __attribute__((ext_vector_type(4))) float f32x4;

__device__ inline ushort f2bf(float f) {
    unsigned b = __float_as_uint(f);
    unsigned r = (b + 0x7FFFu + ((b >> 16) & 1u)) >> 16;
    return (ushort)r;
}
__device__ inline float bf2f(ushort u) {
    return __uint_as_float(((unsigned)u) << 16);
}

// ---- prep: bin (blocks [0,nBin)) + xbf (next nXbf) + wfrag (last) ----------

__global__ __launch_bounds__(256) void prep_kernel(
    const int* __restrict__ src, const int* __restrict__ dst,
    const int* __restrict__ etype, const float* __restrict__ x,
    const float* __restrict__ W1, const float* __restrict__ root1,
    int* __restrict__ gBucketCnt, int2* __restrict__ bucket_buf,
    ushort* __restrict__ xbf, ushort* __restrict__ wf,
    int E, int N, int nBin, int nXbf)
{
    __shared__ int s_k[BK_EDGES];
    __shared__ int s_y[BK_EDGES];
    __shared__ int hist[256], scanv[256], lcur[256], bstart[256], gbase[256];
    const int t = threadIdx.x;
    const int bid = blockIdx.x;

    if (bid >= nBin) {
        if (bid < nBin + nXbf) {          // bf16 copy of x
            int i = (bid - nBin) * 256 + t;
            if (i < N * CH / 4) {
                float4 v = ((const float4*)x)[i];
                ((ushort4*)xbf)[i] = make_ushort4(f2bf(v.x), f2bf(v.y), f2bf(v.z), f2bf(v.w));
            }
        } else {                          // weight B-fragment swizzle (9 mats)
            int idx = (bid - nBin - nXbf) * 256 + t;
            if (idx < 9 * 2 * 4 * 64 * 8) {
                int j    = idx & 7;
                int lane = (idx >> 3) & 63;
                int ct   = (idx >> 9) & 3;
                int ks   = (idx >> 11) & 1;
                int rel  = idx >> 12;
                int k = ks * 32 + (lane >> 4) * 8 + j;
                int n = ct * 16 + (lane & 15);
                float v = (rel < 8) ? W1[((size_t)rel * 64 + k) * 64 + n]
                                    : root1[(size_t)k * 64 + n];
                wf[idx] = f2bf(v);
            }
        }
        return;
    }

    // ---- bin: block-local counting sort by coarse bucket (key>>12) ----
    const int e0 = bid * BK_EDGES;
    const int cnt = min(BK_EDGES, E - e0);

    hist[t] = 0;
    __syncthreads();

    int myb[8], myk[8], myy[8];
    #pragma unroll
    for (int i = 0; i < 8; ++i) {
        int li = t + i * 256;
        if (li < cnt) {
            int e = e0 + li;
            int r = etype[e];
            int k = r * N + dst[e];
            myk[i] = k;
            myy[i] = (r << 17) | src[e];
            myb[i] = k >> 12;
            atomicAdd(&hist[myb[i]], 1);
        } else myb[i] = -1;
    }
    __syncthreads();

    int v = hist[t];
    scanv[t] = v;
    __syncthreads();
    for (int off = 1; off < 256; off <<= 1) {
        int u = (t >= off) ? scanv[t - off] : 0;
        __syncthreads();
        scanv[t] += u;
        __syncthreads();
    }
    int excl = scanv[t] - v;
    bstart[t] = excl;
    lcur[t] = excl;
    __syncthreads();

    #pragma unroll
    for (int i = 0; i < 8; ++i) {
        if (myb[i] >= 0) {
            int p = atomicAdd(&lcur[myb[i]], 1);
            s_k[p] = myk[i];
            s_y[p] = myy[i];
        }
    }
    __syncthreads();

    if (v > 0) gbase[t] = atomicAdd(&gBucketCnt[t], v);
    __syncthreads();

    for (int p = t; p < cnt; p += 256) {
        int k = s_k[p];
        int b = k >> 12;
        int gp = gbase[b] + (p - bstart[b]);
        if (gp < CAP)
            bucket_buf[(size_t)b * CAP + gp] = make_int2(k, s_y[p]);
    }
}

// ---- build: one WG per bucket; self-computed base; LDS hist + scan;
//      coalesced rowptr/inv; LDS-cursor placement; fused kappa atomics -------

__global__ __launch_bounds__(256) void build_kernel(
    const int2* __restrict__ bucket_buf, const int* __restrict__ gBucketCnt,
    int* __restrict__ rowptr, float* __restrict__ inv,
    int* __restrict__ perm, float* __restrict__ kappa, int N)
{
    __shared__ int hist[4096];
    __shared__ int cur[4096];
    __shared__ int part[256];
    const int b = blockIdx.x;
    const int t = threadIdx.x;
    const int nb = min(gBucketCnt[b], CAP);
    const int2* rec = bucket_buf + (size_t)b * CAP;

    // bucket base = exclusive prefix of gBucketCnt over buckets
    int bc = gBucketCnt[t];
    part[t] = bc;
    __syncthreads();
    for (int off = 1; off < 256; off <<= 1) {
        int u = (t >= off) ? part[t - off] : 0;
        __syncthreads();
        part[t] += u;
        __syncthreads();
    }
    __shared__ int baseS;
    if (t == b) baseS = part[t] - bc;
    __syncthreads();
    const int base = baseS;

    for (int i = t; i < 4096; i += 256) hist[i] = 0;
    __syncthreads();
    for (int j = t; j < nb; j += 256) atomicAdd(&hist[rec[j].x & 4095], 1);
    __syncthreads();

    const int i0 = t * 16;
    int s = 0;
    #pragma unroll
    for (int k = 0; k < 16; ++k) s += hist[i0 + k];
    part[t] = s;
    __syncthreads();
    for (int off = 1; off < 256; off <<= 1) {
        int u = (t >= off) ? part[t - off] : 0;
        __syncthreads();
        part[t] += u;
        __syncthreads();
    }
    int run = base + part[t] - s;
    #pragma unroll
    for (int k = 0; k < 16; ++k) {
        int c = hist[i0 + k];
        cur[i0 + k] = run;
        rowptr[b * 4096 + i0 + k] = run;
        inv[b * 4096 + i0 + k] = 1.0f / (float)max(c, 1);
        run += c;
    }
    __syncthreads();

    for (int j = t; j < nb; j += 256) {
        int k = rec[j].x, y = rec[j].y;
        int lk = k & 4095;
        int pos = atomicAdd(&cur[lk], 1);      // LDS cursor
        int sr = y & 0x1FFFF;
        int r = y >> 17;
        perm[pos] = sr;                        // 32KB-window write (local)
        unsafeAtomicAdd(&kappa[(sr << 3) | r], 1.0f / (float)max(hist[lk], 1));
    }
}

// ---- fused layer 1 ----------------------------------------------------------
// one wave per 16-node tile. Relations processed in pairs (2p,2p+1): lane sg
// walks FOUR segments (2 rels x nodes sg,sg+8) as interleaved independent
// chains (register accumulation, perm prefetch), packs two bf16 A-tiles,
// then 16x16x32 bf16 MFMA for both relations vs pre-swizzled W frags.

__global__ __launch_bounds__(256) void rgcn1_fused_kernel(
    const int* __restrict__ rowptr, const int* __restrict__ perm,
    const float* __restrict__ inv, const ushort* __restrict__ xbf,
    const ushort* __restrict__ wfrag, const float* __restrict__ b1,
    float* __restrict__ h, int N)
{
    __shared__ ushort Abuf[4][2][16 * 72];  // two 16x64 bf16 A-tiles per wave
    __shared__ int    rpS[4][144];          // rowptr[r*N+base+mm], i = r*17+mm
    __shared__ float  invS[4][128];         // inv[r*N+base+m],     i = r*16+m
    const int widx = threadIdx.x >> 6;
    const int lane = threadIdx.x & 63;
    const int wid = (blockIdx.x << 2) | widx;
    const int base = wid << 4;
    if (base >= N) return;

    const int m0 = lane & 15;
    const int q  = lane >> 4;
    const int sg = lane >> 3;
    const int cg = lane & 7;
    ushort* ab0 = Abuf[widx][0];
    ushort* ab1 = Abuf[widx][1];
    int*    rpL = rpS[widx];
    float*  ivL = invS[widx];

    for (int i = lane; i < 136; i += 64) {
        int r = i / 17, mm = i - r * 17;
        rpL[i] = rowptr[(size_t)r * N + base + mm];
    }
    for (int i = lane; i < 128; i += 64)
        ivL[i] = inv[(size_t)(i >> 4) * N + base + (i & 15)];

    f32x4 acc4[4];
    #pragma unroll
    for (int ct = 0; ct < 4; ++ct) acc4[ct] = (f32x4)(0.0f);

    for (int rp = 0; rp < 4; ++rp) {
        const int r0 = rp * 2, r1 = r0 + 1;
        const int iA = r0 * 17 + sg,     iB = iA + 8;
        const int iC = r1 * 17 + sg,     iD = iC + 8;
        int jA = rpL[iA], eA = rpL[iA + 1];
        int jB = rpL[iB], eB = rpL[iB + 1];
        int jC = rpL[iC], eC = rpL[iC + 1];
        int jD = rpL[iD], eD = rpL[iD + 1];
        float a[8] = {}, b[8] = {}, c[8] = {}, d[8] = {};
        int sA = (jA < eA) ? perm[jA] : 0;
        int sB = (jB < eB) ? perm[jB] : 0;
        int sC = (jC < eC) ? perm[jC] : 0;
        int sD = (jD < eD) ? perm[jD] : 0;
        while ((jA < eA) | (jB < eB) | (jC < eC) | (jD < eD)) {
            bool vA = jA < eA, vB = jB < eB, vC = jC < eC, vD = jD < eD;
            short8 rA = {}, rB = {}, rC = {}, rD = {};
            if (vA) rA = *(const short8*)&xbf[(size_t)sA * CH + (cg << 3)];
            if (vB) rB = *(const short8*)&xbf[(size_t)sB * CH + (cg << 3)];
            if (vC) rC = *(const short8*)&xbf[(size_t)sC * CH + (cg << 3)];
            if (vD) rD = *(const short8*)&xbf[(size_t)sD * CH + (cg << 3)];
            if (jA + 1 < eA) sA = perm[jA + 1];   // prefetch next src
            if (jB + 1 < eB) sB = perm[jB + 1];
            if (jC + 1 < eC) sC = perm[jC + 1];
            if (jD + 1 < eD) sD = perm[jD + 1];
            if (vA) {
                #pragma unroll
                for (int k = 0; k < 8; ++k) a[k] += bf2f((ushort)rA[k]);
                ++jA;
            }
            if (vB) {
                #pragma unroll
                for (int k = 0; k < 8; ++k) b[k] += bf2f((ushort)rB[k]);
                ++jB;
            }
            if (vC) {
                #pragma unroll
                for (int k = 0; k < 8; ++k) c[k] += bf2f((ushort)rC[k]);
                ++jC;
            }
            if (vD) {
                #pragma unroll
                for (int k = 0; k < 8; ++k) d[k] += bf2f((ushort)rD[k]);
                ++jD;
            }
        }
        const float ivA = ivL[(r0 << 4) | sg];
        const float ivB = ivL[(r0 << 4) | (8 + sg)];
        const float ivC = ivL[(r1 << 4) | sg];
        const float ivD = ivL[(r1 << 4) | (8 + sg)];
        short8 oA, oB, oC, oD;
        #pragma unroll
        for (int k = 0; k < 8; ++k) {
            oA[k] = (short)f2bf(a[k] * ivA);
            oB[k] = (short)f2bf(b[k] * ivB);
            oC[k] = (short)f2bf(c[k] * ivC);
            oD[k] = (short)f2bf(d[k] * ivD);
        }
        *(short8*)&ab0[sg * 72 + (cg << 3)]       = oA;
        *(short8*)&ab0[(8 + sg) * 72 + (cg << 3)] = oB;
        *(short8*)&ab1[sg * 72 + (cg << 3)]       = oC;
        *(short8*)&ab1[(8 + sg) * 72 + (cg << 3)] = oD;

        // MFMA: 2 K-steps x 4 col-tiles for each relation of the pair
        #pragma unroll
        for (int s = 0; s < 2; ++s) {
            short8 av0 = *(short8*)&ab0[m0 * 72 + s * 32 + q * 8];
            #pragma unroll
            for (int ct = 0; ct < 4; ++ct) {
                short8 bv = *(const short8*)&wfrag[(((size_t)(r0 * 2 + s) * 4 + ct) * 64 + lane) * 8];
                acc4[ct] = __builtin_amdgcn_mfma_f32_16x16x32_bf16(av0, bv, acc4[ct], 0, 0, 0);
            }
            short8 av1 = *(short8*)&ab1[m0 * 72 + s * 32 + q * 8];
            #pragma unroll
            for (int ct = 0; ct < 4; ++ct) {
                short8 bv = *(const short8*)&wfrag[(((size_t)(r1 * 2 + s) * 4 + ct) * 64 + lane) * 8];
                acc4[ct] = __builtin_amdgcn_mfma_f32_16x16x32_bf16(av1, bv, acc4[ct], 0, 0, 0);
            }
        }
    }

    {   // root: A-frag = x rows directly (rel index 8 in wfrag)
        int node = min(base + m0, N - 1);
        #pragma unroll
        for (int s = 0; s < 2; ++s) {
            short8 av = *(const short8*)&xbf[(size_t)node * CH + s * 32 + q * 8];
            #pragma unroll
            for (int ct = 0; ct < 4; ++ct) {
                short8 bv = *(const short8*)&wfrag[(((size_t)(8 * 2 + s) * 4 + ct) * 64 + lane) * 8];
                acc4[ct] = __builtin_amdgcn_mfma_f32_16x16x32_bf16(av, bv, acc4[ct], 0, 0, 0);
            }
        }
    }

    // epilogue: D[row=q*4+v][col=ct*16+m0]
    #pragma unroll
    for (int ct = 0; ct < 4; ++ct) {
        int cc = ct * 16 + m0;
        float bb = b1[cc];
        #pragma unroll
        for (int v = 0; v < 4; ++v) {
            int node = base + q * 4 + v;
            if (node < N)
                h[(size_t)node * CH + cc] = fmaxf(acc4[ct][v] + bb, 0.f);
        }
    }
}

// ---- layer-2 collapse -------------------------------------------------------

__global__ __launch_bounds__(256) void kred_kernel(
    const float* __restrict__ h, const float* __restrict__ kappa,
    float* __restrict__ sacc, int N)
{
    const int lane = threadIdx.x & 63;
    const int w = threadIdx.x >> 6;
    int wave = (blockIdx.x << 2) | w;
    const int wstride = gridDim.x << 2;
    float racc[9] = {};
    for (int i = wave; i < N; i += wstride) {
        float hv = h[(size_t)i * CH + lane];
        #pragma unroll
        for (int r = 0; r < 8; ++r) racc[r] += hv * kappa[i * 8 + r];
        racc[8] += hv;
    }
    __shared__ float red[4][9][64];
    #pragma unroll
    for (int r = 0; r < 9; ++r) red[w][r][lane] = racc[r];
    __syncthreads();
    if (w == 0) {
        #pragma unroll
        for (int r = 0; r < 9; ++r) {
            float s4 = red[0][r][lane] + red[1][r][lane] + red[2][r][lane] + red[3][r][lane];
            unsafeAtomicAdd(&sacc[r * 64 + lane], s4);
        }
    }
}

__global__ void finalize_kernel(const float* __restrict__ sacc, const float* __restrict__ root2,
                                const float* __restrict__ W2, const float* __restrict__ b2,
                                float* __restrict__ out, float invN)
{
    __shared__ float g[16];
    int t = threadIdx.x;
    if (t < 16) {
        const float* s0 = sacc + 512;
        float acc = 0.f;
        for (int c = 0; c < 64; ++c) acc += s0[c] * root2[c * 16 + t];
        for (int r = 0; r < 8; ++r) {
            const float* sr = sacc + r * 64;
            for (int c = 0; c < 64; ++c) acc += sr[c] * W2[(r * 64 + c) * 16 + t];
        }
        g[t] = acc * invN + b2[t];
    }
    __syncthreads();
    if (t < 16) {
        float m = -1e30f;
        for (int i = 0; i < 16; ++i) m = fmaxf(m, g[i]);
        float s = 0.f;
        for (int i = 0; i < 16; ++i) s += expf(g[i] - m);
        out[t] = g[t] - (m + logf(s));
    }
}

// ---- launch -----------------------------------------------------------------

extern "C" void kernel_launch(void* const* d_in, const int* in_sizes, int n_in,
                              void* d_out, int out_size, void* d_ws, size_t ws_size,
                              hipStream_t stream)
{
    const float* x     = (const float*)d_in[0];
    const int*   eidx  = (const int*)d_in[1];
    const int*   etype = (const int*)d_in[2];
    const float* W1    = (const float*)d_in[3];
    const float* root1 = (const float*)d_in[4];
    const float* b1    = (const float*)d_in[5];
    const float* W2    = (const float*)d_in[6];
    const float* root2 = (const float*)d_in[7];
    const float* b2    = (const float*)d_in[8];
    float* out = (float*)d_out;

    const int E = in_sizes[1] / 2;
    const int N = in_sizes[0] / CH;
    const int NKEY = N * 8;
    const int NBUK = (NKEY + 4095) / 4096;         // 196 for N=100K (<=256)
    const int KSPACE = NBUK << 12;
    const int* srcI = eidx;
    const int* dstI = eidx + E;

    // workspace layout (4B units):
    // [gBucketCnt 256 | sacc 576 | kappa NKEY]   <- zeroed prefix
    // [inv KSPACE | rowptr KSPACE+16 | perm E | bucket_buf (8B-al) NBUK*CAP*2 |
    //  xbf N*CH/2 | wfrag 18432 | h N*CH]
    int* wsi = (int*)d_ws;
    int*   gBucketCnt = wsi;
    float* sacc       = (float*)(gBucketCnt + 256);
    float* kappa      = sacc + 576;
    float* inv        = kappa + NKEY;
    int*   rowptr     = (int*)(inv + KSPACE);
    int*   perm       = rowptr + KSPACE + 16;
    size_t off = (size_t)((perm + E) - wsi);
    off = (off + 1) & ~(size_t)1;                  // 8B-align
    int2*  bucket_buf = (int2*)(wsi + off);
    off += (size_t)NBUK * CAP * 2;
    off = (off + 7) & ~(size_t)7;                  // 32B-align
    ushort* xbf = (ushort*)(wsi + off);
    ushort* wfg = xbf + (size_t)N * CH;
    float*  h   = (float*)(wfg + 36864);

    hipMemsetAsync(d_ws, 0, (size_t)(256 + 576 + NKEY) * 4, stream);

    const int nBin = (E + BK_EDGES - 1) / BK_EDGES;
    const int nXbf = (N * CH / 4 + 255) / 256;
    const int nWf  = (36864 + 255) / 256;
    prep_kernel<<<nBin + nXbf + nWf, 256, 0, stream>>>(
        srcI, dstI, etype, x, W1, root1, gBucketCnt, bucket_buf, xbf, wfg,
        E, N, nBin, nXbf);

    build_kernel<<<NBUK, 256, 0, stream>>>(
        bucket_buf, gBucketCnt, rowptr, inv, perm, kappa, N);

    const int tiles = (N + 15) / 16;
    rgcn1_fused_kernel<<<(tiles + 3) / 4, 256, 0, stream>>>(
        rowptr, perm, inv, xbf, wfg, b1, h, N);

    kred_kernel<<<1024, 256, 0, stream>>>(h, kappa, sacc, N);
    finalize_kernel<<<1, 64, 0, stream>>>(sacc, root2, W2, b2, out, 1.0f / (float)N);
}

// Round 12
// 408.959 us; speedup vs baseline: 1.0216x; 1.0216x over previous
//
#include <hip/hip_runtime.h>
#include <hip/hip_bf16.h>

// RGCN 2-layer + global mean pool + log_softmax. Round 12.
// - fused gather reverted to R9 2-chain walk (R11's 4-chain cost VGPR 72 /
//   occupancy 23% -> regressed; 2 chains @ 33% occ wins).
// - layer-2 collapse (kred) folded into fused epilogue via kappa; h buffer
//   eliminated entirely (no 25.6MB write + 25.6MB read).
// - bucket granularity 4096 -> 1024 keys: build runs 782 blocks (~3/CU)
//   instead of 196 (<1/CU).

#define CH 64
#define BK_EDGES 2048
#define BSH 10
#define NBINS 1024
#define CAP 3072    // per-bucket record capacity (avg ~2046, +22 sigma)

typedef __attribute__((ext_vector_type(8))) short short8;
typedef __attribute__((ext_vector_type(4))) float f32x4;

__device__ inline ushort f2bf(float f) {
    unsigned b = __float_as_uint(f);
    unsigned r = (b + 0x7FFFu + ((b >> 16) & 1u)) >> 16;
    return (ushort)r;
}
__device__ inline float bf2f(ushort u) {
    return __uint_as_float(((unsigned)u) << 16);
}

// ---- prep: bin (blocks [0,nBin)) + xbf (next nXbf) + wfrag (last) ----------

__global__ __launch_bounds__(256) void prep_kernel(
    const int* __restrict__ src, const int* __restrict__ dst,
    const int* __restrict__ etype, const float* __restrict__ x,
    const float* __restrict__ W1, const float* __restrict__ root1,
    int* __restrict__ gBucketCnt, int2* __restrict__ bucket_buf,
    ushort* __restrict__ xbf, ushort* __restrict__ wf,
    int E, int N, int nBin, int nXbf)
{
    __shared__ int s_k[BK_EDGES];
    __shared__ int s_y[BK_EDGES];
    __shared__ int hist[NBINS], lcur[NBINS], bstart[NBINS], gbase[NBINS];
    __shared__ int scanv[256];
    const int t = threadIdx.x;
    const int bid = blockIdx.x;

    if (bid >= nBin) {
        if (bid < nBin + nXbf) {          // bf16 copy of x
            int i = (bid - nBin) * 256 + t;
            if (i < N * CH / 4) {
                float4 v = ((const float4*)x)[i];
                ((ushort4*)xbf)[i] = make_ushort4(f2bf(v.x), f2bf(v.y), f2bf(v.z), f2bf(v.w));
            }
        } else {                          // weight B-fragment swizzle (9 mats)
            int idx = (bid - nBin - nXbf) * 256 + t;
            if (idx < 9 * 2 * 4 * 64 * 8) {
                int j    = idx & 7;
                int lane = (idx >> 3) & 63;
                int ct   = (idx >> 9) & 3;
                int ks   = (idx >> 11) & 1;
                int rel  = idx >> 12;
                int k = ks * 32 + (lane >> 4) * 8 + j;
                int n = ct * 16 + (lane & 15);
                float v = (rel < 8) ? W1[((size_t)rel * 64 + k) * 64 + n]
                                    : root1[(size_t)k * 64 + n];
                wf[idx] = f2bf(v);
            }
        }
        return;
    }

    // ---- bin: block-local counting sort by coarse bucket (key>>BSH) ----
    const int e0 = bid * BK_EDGES;
    const int cnt = min(BK_EDGES, E - e0);

    for (int i = t; i < NBINS; i += 256) hist[i] = 0;
    __syncthreads();

    int myb[8], myk[8], myy[8];
    #pragma unroll
    for (int i = 0; i < 8; ++i) {
        int li = t + i * 256;
        if (li < cnt) {
            int e = e0 + li;
            int r = etype[e];
            int k = r * N + dst[e];
            myk[i] = k;
            myy[i] = (r << 17) | src[e];
            myb[i] = k >> BSH;
            atomicAdd(&hist[myb[i]], 1);
        } else myb[i] = -1;
    }
    __syncthreads();

    // exclusive scan over 1024 bins, 4 per thread
    const int i0 = t * 4;
    int c0 = hist[i0], c1 = hist[i0 + 1], c2 = hist[i0 + 2], c3 = hist[i0 + 3];
    int s = c0 + c1 + c2 + c3;
    scanv[t] = s;
    __syncthreads();
    for (int off = 1; off < 256; off <<= 1) {
        int u = (t >= off) ? scanv[t - off] : 0;
        __syncthreads();
        scanv[t] += u;
        __syncthreads();
    }
    int excl = scanv[t] - s;
    bstart[i0] = excl;               lcur[i0] = excl;
    bstart[i0 + 1] = excl + c0;      lcur[i0 + 1] = excl + c0;
    bstart[i0 + 2] = excl + c0 + c1; lcur[i0 + 2] = excl + c0 + c1;
    bstart[i0 + 3] = excl + c0 + c1 + c2; lcur[i0 + 3] = excl + c0 + c1 + c2;
    __syncthreads();

    #pragma unroll
    for (int i = 0; i < 8; ++i) {
        if (myb[i] >= 0) {
            int p = atomicAdd(&lcur[myb[i]], 1);
            s_k[p] = myk[i];
            s_y[p] = myy[i];
        }
    }
    __syncthreads();

    #pragma unroll
    for (int k = 0; k < 4; ++k) {
        int bb = i0 + k;
        int cb = hist[bb];
        if (cb > 0) gbase[bb] = atomicAdd(&gBucketCnt[bb], cb);
    }
    __syncthreads();

    for (int p = t; p < cnt; p += 256) {
        int k = s_k[p];
        int b = k >> BSH;
        int gp = gbase[b] + (p - bstart[b]);
        if (gp < CAP)
            bucket_buf[(size_t)b * CAP + gp] = make_int2(k, s_y[p]);
    }
}

// ---- build: one WG per bucket (782); self-computed base; LDS hist + scan;
//      coalesced rowptr/inv; LDS-cursor placement; fused kappa atomics -------

__global__ __launch_bounds__(256) void build_kernel(
    const int2* __restrict__ bucket_buf, const int* __restrict__ gBucketCnt,
    int* __restrict__ rowptr, float* __restrict__ inv,
    int* __restrict__ perm, float* __restrict__ kappa, int N, int NBUK)
{
    __shared__ int hist[NBINS];
    __shared__ int cur[NBINS];
    __shared__ int part[256];
    const int b = blockIdx.x;
    const int t = threadIdx.x;
    const int nb = min(gBucketCnt[b], CAP);
    const int2* rec = bucket_buf + (size_t)b * CAP;
    const int i0 = t * 4;

    // bucket base = exclusive prefix of gBucketCnt (NBUK entries, 4/thread)
    int c[4]; int s = 0;
    #pragma unroll
    for (int k = 0; k < 4; ++k) {
        c[k] = (i0 + k < NBUK) ? gBucketCnt[i0 + k] : 0;
        s += c[k];
    }
    part[t] = s;
    __syncthreads();
    for (int off = 1; off < 256; off <<= 1) {
        int u = (t >= off) ? part[t - off] : 0;
        __syncthreads();
        part[t] += u;
        __syncthreads();
    }
    int run = part[t] - s;
    #pragma unroll
    for (int k = 0; k < 4; ++k) { cur[i0 + k] = run; run += c[k]; }
    __syncthreads();
    const int base = cur[b];
    __syncthreads();

    for (int i = t; i < NBINS; i += 256) hist[i] = 0;
    __syncthreads();
    for (int j = t; j < nb; j += 256) atomicAdd(&hist[rec[j].x & (NBINS - 1)], 1);
    __syncthreads();

    int h0 = hist[i0], h1 = hist[i0 + 1], h2 = hist[i0 + 2], h3 = hist[i0 + 3];
    int s2 = h0 + h1 + h2 + h3;
    part[t] = s2;
    __syncthreads();
    for (int off = 1; off < 256; off <<= 1) {
        int u = (t >= off) ? part[t - off] : 0;
        __syncthreads();
        part[t] += u;
        __syncthreads();
    }
    run = base + part[t] - s2;
    int hk[4] = {h0, h1, h2, h3};
    #pragma unroll
    for (int k = 0; k < 4; ++k) {
        cur[i0 + k] = run;
        rowptr[b * NBINS + i0 + k] = run;
        inv[b * NBINS + i0 + k] = 1.0f / (float)max(hk[k], 1);
        run += hk[k];
    }
    __syncthreads();

    for (int j = t; j < nb; j += 256) {
        int k = rec[j].x, y = rec[j].y;
        int lk = k & (NBINS - 1);
        int pos = atomicAdd(&cur[lk], 1);      // LDS cursor
        int sr = y & 0x1FFFF;
        int r = y >> 17;
        perm[pos] = sr;
        unsafeAtomicAdd(&kappa[(sr << 3) | r], 1.0f / (float)max(hist[lk], 1));
    }
}

// ---- fused layer 1 + layer-2 collapse ---------------------------------------
// one wave per 16-node tile. R9 2-chain segment walk + MFMA; epilogue computes
// h in registers, drops it to LDS (bf16), and reduces s_r[c] += h*kappa and
// s0[c] += h per column -> block reduce -> global atomics. No h buffer.

__global__ __launch_bounds__(256) void rgcn1_fused_kernel(
    const int* __restrict__ rowptr, const int* __restrict__ perm,
    const float* __restrict__ inv, const ushort* __restrict__ xbf,
    const ushort* __restrict__ wfrag, const float* __restrict__ b1,
    const float* __restrict__ kappa, float* __restrict__ sacc, int N)
{
    __shared__ ushort Abuf[4][16 * 72];
    __shared__ int    rpS[4][144];
    __shared__ float  invS[4][128];
    __shared__ float  kapS[4][128];
    __shared__ float  red[4][9][64];
    const int widx = threadIdx.x >> 6;
    const int lane = threadIdx.x & 63;
    const int wid = (blockIdx.x << 2) | widx;
    const int base = wid << 4;
    const bool wvalid = base < N;

    const int m0 = lane & 15;
    const int q  = lane >> 4;
    const int sg = lane >> 3;
    const int cg = lane & 7;
    ushort* ab = Abuf[widx];
    int*    rpL = rpS[widx];
    float*  ivL = invS[widx];
    float*  kpL = kapS[widx];

    float sr[9] = {};

    if (wvalid) {
        for (int i = lane; i < 136; i += 64) {
            int r = i / 17, mm = i - r * 17;
            rpL[i] = rowptr[(size_t)r * N + base + mm];
        }
        for (int i = lane; i < 128; i += 64) {
            ivL[i] = inv[(size_t)(i >> 4) * N + base + (i & 15)];
            kpL[i] = kappa[(size_t)(base + (i >> 3)) * 8 + (i & 7)];
        }

        f32x4 acc4[4];
        #pragma unroll
        for (int ct = 0; ct < 4; ++ct) acc4[ct] = (f32x4)(0.0f);

        for (int r = 0; r < 8; ++r) {
            const int iA = r * 17 + sg;
            const int iB = iA + 8;
            int jA = rpL[iA], eA = rpL[iA + 1];
            int jB = rpL[iB], eB = rpL[iB + 1];
            float a[8] = {}, bacc[8] = {};
            int sA = (jA < eA) ? perm[jA] : 0;
            int sB = (jB < eB) ? perm[jB] : 0;
            while (jA < eA || jB < eB) {
                bool vA = jA < eA, vB = jB < eB;
                short8 rA = {}, rB = {};
                if (vA) rA = *(const short8*)&xbf[(size_t)sA * CH + (cg << 3)];
                if (vB) rB = *(const short8*)&xbf[(size_t)sB * CH + (cg << 3)];
                if (jA + 1 < eA) sA = perm[jA + 1];     // prefetch next src
                if (jB + 1 < eB) sB = perm[jB + 1];
                if (vA) {
                    #pragma unroll
                    for (int k = 0; k < 8; ++k) a[k] += bf2f((ushort)rA[k]);
                    ++jA;
                }
                if (vB) {
                    #pragma unroll
                    for (int k = 0; k < 8; ++k) bacc[k] += bf2f((ushort)rB[k]);
                    ++jB;
                }
            }
            const float ivA = ivL[(r << 4) | sg];
            const float ivB = ivL[(r << 4) | (8 + sg)];
            short8 oA, oB;
            #pragma unroll
            for (int k = 0; k < 8; ++k) {
                oA[k] = (short)f2bf(a[k] * ivA);
                oB[k] = (short)f2bf(bacc[k] * ivB);
            }
            *(short8*)&ab[sg * 72 + (cg << 3)]       = oA;
            *(short8*)&ab[(8 + sg) * 72 + (cg << 3)] = oB;

            #pragma unroll
            for (int s = 0; s < 2; ++s) {
                short8 av = *(short8*)&ab[m0 * 72 + s * 32 + q * 8];
                #pragma unroll
                for (int ct = 0; ct < 4; ++ct) {
                    short8 bv = *(const short8*)&wfrag[(((size_t)(r * 2 + s) * 4 + ct) * 64 + lane) * 8];
                    acc4[ct] = __builtin_amdgcn_mfma_f32_16x16x32_bf16(av, bv, acc4[ct], 0, 0, 0);
                }
            }
        }

        {   // root: A-frag = x rows directly (rel index 8 in wfrag)
            int node = min(base + m0, N - 1);
            #pragma unroll
            for (int s = 0; s < 2; ++s) {
                short8 av = *(const short8*)&xbf[(size_t)node * CH + s * 32 + q * 8];
                #pragma unroll
                for (int ct = 0; ct < 4; ++ct) {
                    short8 bv = *(const short8*)&wfrag[(((size_t)(8 * 2 + s) * 4 + ct) * 64 + lane) * 8];
                    acc4[ct] = __builtin_amdgcn_mfma_f32_16x16x32_bf16(av, bv, acc4[ct], 0, 0, 0);
                }
            }
        }

        // epilogue: h[row=q*4+v][col=ct*16+m0] = relu(acc+b1) -> LDS (bf16)
        #pragma unroll
        for (int ct = 0; ct < 4; ++ct) {
            int cc = ct * 16 + m0;
            float bb = b1[cc];
            #pragma unroll
            for (int v = 0; v < 4; ++v) {
                int node = base + q * 4 + v;
                float hv = (node < N) ? fmaxf(acc4[ct][v] + bb, 0.f) : 0.f;
                ab[(q * 4 + v) * 72 + cc] = f2bf(hv);
            }
        }
        // column reduce (lane = column): sr[r] = sum_m h[m][lane]*kappa[m][r]
        #pragma unroll
        for (int m = 0; m < 16; ++m) {
            float hv = bf2f(ab[m * 72 + lane]);
            #pragma unroll
            for (int r = 0; r < 8; ++r) sr[r] += hv * kpL[m * 8 + r];
            sr[8] += hv;
        }
    }

    #pragma unroll
    for (int r = 0; r < 9; ++r) red[widx][r][lane] = sr[r];
    __syncthreads();
    if (widx == 0) {
        #pragma unroll
        for (int r = 0; r < 9; ++r) {
            float s4 = red[0][r][lane] + red[1][r][lane] + red[2][r][lane] + red[3][r][lane];
            unsafeAtomicAdd(&sacc[r * 64 + lane], s4);   // r=8 -> s0 slot 512+lane
        }
    }
}

// g[o] = (s0@root2 + sum_r s_r@W2[r]) / N + b2;  out = log_softmax(g)
__global__ void finalize_kernel(const float* __restrict__ sacc, const float* __restrict__ root2,
                                const float* __restrict__ W2, const float* __restrict__ b2,
                                float* __restrict__ out, float invN)
{
    __shared__ float g[16];
    int t = threadIdx.x;
    if (t < 16) {
        const float* s0 = sacc + 512;
        float acc = 0.f;
        for (int c = 0; c < 64; ++c) acc += s0[c] * root2[c * 16 + t];
        for (int r = 0; r < 8; ++r) {
            const float* sr = sacc + r * 64;
            for (int c = 0; c < 64; ++c) acc += sr[c] * W2[(r * 64 + c) * 16 + t];
        }
        g[t] = acc * invN + b2[t];
    }
    __syncthreads();
    if (t < 16) {
        float m = -1e30f;
        for (int i = 0; i < 16; ++i) m = fmaxf(m, g[i]);
        float s = 0.f;
        for (int i = 0; i < 16; ++i) s += expf(g[i] - m);
        out[t] = g[t] - (m + logf(s));
    }
}

// ---- launch -----------------------------------------------------------------

extern "C" void kernel_launch(void* const* d_in, const int* in_sizes, int n_in,
                              void* d_out, int out_size, void* d_ws, size_t ws_size,
                              hipStream_t stream)
{
    const float* x     = (const float*)d_in[0];
    const int*   eidx  = (const int*)d_in[1];
    const int*   etype = (const int*)d_in[2];
    const float* W1    = (const float*)d_in[3];
    const float* root1 = (const float*)d_in[4];
    const float* b1    = (const float*)d_in[5];
    const float* W2    = (const float*)d_in[6];
    const float* root2 = (const float*)d_in[7];
    const float* b2    = (const float*)d_in[8];
    float* out = (float*)d_out;

    const int E = in_sizes[1] / 2;
    const int N = in_sizes[0] / CH;
    const int NKEY = N * 8;
    const int NBUK = (NKEY + NBINS - 1) / NBINS;   // 782 for N=100K (<=1024)
    const int KSPACE = NBUK * NBINS;
    const int* srcI = eidx;
    const int* dstI = eidx + E;

    // workspace layout (4B units):
    // [gBucketCnt 1024 | sacc 576 | kappa NKEY]   <- zeroed prefix
    // [inv KSPACE | rowptr KSPACE+16 | perm E | bucket_buf (8B-al) NBUK*CAP*2 |
    //  xbf N*CH/2 | wfrag 18432]
    int* wsi = (int*)d_ws;
    int*   gBucketCnt = wsi;
    float* sacc       = (float*)(gBucketCnt + 1024);
    float* kappa      = sacc + 576;
    float* inv        = kappa + NKEY;
    int*   rowptr     = (int*)(inv + KSPACE);
    int*   perm       = rowptr + KSPACE + 16;
    size_t off = (size_t)((perm + E) - wsi);
    off = (off + 1) & ~(size_t)1;                  // 8B-align
    int2*  bucket_buf = (int2*)(wsi + off);
    off += (size_t)NBUK * CAP * 2;
    off = (off + 7) & ~(size_t)7;                  // 32B-align
    ushort* xbf = (ushort*)(wsi + off);
    ushort* wfg = xbf + (size_t)N * CH;

    hipMemsetAsync(d_ws, 0, (size_t)(1024 + 576 + NKEY) * 4, stream);

    const int nBin = (E + BK_EDGES - 1) / BK_EDGES;
    const int nXbf = (N * CH / 4 + 255) / 256;
    const int nWf  = (36864 + 255) / 256;
    prep_kernel<<<nBin + nXbf + nWf, 256, 0, stream>>>(
        srcI, dstI, etype, x, W1, root1, gBucketCnt, bucket_buf, xbf, wfg,
        E, N, nBin, nXbf);

    build_kernel<<<NBUK, 256, 0, stream>>>(
        bucket_buf, gBucketCnt, rowptr, inv, perm, kappa, N, NBUK);

    const int tiles = (N + 15) / 16;
    rgcn1_fused_kernel<<<(tiles + 3) / 4, 256, 0, stream>>>(
        rowptr, perm, inv, xbf, wfg, b1, kappa, sacc, N);

    finalize_kernel<<<1, 64, 0, stream>>>(sacc, root2, W2, b2, out, 1.0f / (float)N);
}

// Round 13
// 339.033 us; speedup vs baseline: 1.2323x; 1.2063x over previous
//
#include <hip/hip_runtime.h>
#include <hip/hip_bf16.h>

// RGCN 2-layer + global mean pool + log_softmax. Round 13.
// Base = R9 (377us measured): 4096-key buckets (196 blocks), separate kred,
// h buffer, fused 2-chain walk. Change: depth-2 prefetch per chain -- rows
// j and j+1 of each segment in flight simultaneously, branchless masked
// accumulate. 32 row-streams/wave vs 16, epochs halved, accumulators kept
// at 2 sets (R11's 4-set VGPR blowup regressed).

#define CH 64
#define BK_EDGES 2048
#define CAP 12288   // per-bucket record capacity (avg ~8163, >40 sigma)

typedef __attribute__((ext_vector_type(8))) short short8;
typedef __attribute__((ext_vector_type(4))) float f32x4;

__device__ inline ushort f2bf(float f) {
    unsigned b = __float_as_uint(f);
    unsigned r = (b + 0x7FFFu + ((b >> 16) & 1u)) >> 16;
    return (ushort)r;
}
__device__ inline float bf2f(ushort u) {
    return __uint_as_float(((unsigned)u) << 16);
}

// ---- prep: bin (blocks [0,nBin)) + xbf (next nXbf) + wfrag (last) ----------

__global__ __launch_bounds__(256) void prep_kernel(
    const int* __restrict__ src, const int* __restrict__ dst,
    const int* __restrict__ etype, const float* __restrict__ x,
    const float* __restrict__ W1, const float* __restrict__ root1,
    int* __restrict__ gBucketCnt, int2* __restrict__ bucket_buf,
    ushort* __restrict__ xbf, ushort* __restrict__ wf,
    int E, int N, int nBin, int nXbf)
{
    __shared__ int s_k[BK_EDGES];
    __shared__ int s_y[BK_EDGES];
    __shared__ int hist[256], scanv[256], lcur[256], bstart[256], gbase[256];
    const int t = threadIdx.x;
    const int bid = blockIdx.x;

    if (bid >= nBin) {
        if (bid < nBin + nXbf) {          // bf16 copy of x
            int i = (bid - nBin) * 256 + t;
            if (i < N * CH / 4) {
                float4 v = ((const float4*)x)[i];
                ((ushort4*)xbf)[i] = make_ushort4(f2bf(v.x), f2bf(v.y), f2bf(v.z), f2bf(v.w));
            }
        } else {                          // weight B-fragment swizzle (9 mats)
            int idx = (bid - nBin - nXbf) * 256 + t;
            if (idx < 9 * 2 * 4 * 64 * 8) {
                int j    = idx & 7;
                int lane = (idx >> 3) & 63;
                int ct   = (idx >> 9) & 3;
                int ks   = (idx >> 11) & 1;
                int rel  = idx >> 12;
                int k = ks * 32 + (lane >> 4) * 8 + j;
                int n = ct * 16 + (lane & 15);
                float v = (rel < 8) ? W1[((size_t)rel * 64 + k) * 64 + n]
                                    : root1[(size_t)k * 64 + n];
                wf[idx] = f2bf(v);
            }
        }
        return;
    }

    // ---- bin: block-local counting sort by coarse bucket (key>>12) ----
    const int e0 = bid * BK_EDGES;
    const int cnt = min(BK_EDGES, E - e0);

    hist[t] = 0;
    __syncthreads();

    int myb[8], myk[8], myy[8];
    #pragma unroll
    for (int i = 0; i < 8; ++i) {
        int li = t + i * 256;
        if (li < cnt) {
            int e = e0 + li;
            int r = etype[e];
            int k = r * N + dst[e];
            myk[i] = k;
            myy[i] = (r << 17) | src[e];
            myb[i] = k >> 12;
            atomicAdd(&hist[myb[i]], 1);
        } else myb[i] = -1;
    }
    __syncthreads();

    int v = hist[t];
    scanv[t] = v;
    __syncthreads();
    for (int off = 1; off < 256; off <<= 1) {
        int u = (t >= off) ? scanv[t - off] : 0;
        __syncthreads();
        scanv[t] += u;
        __syncthreads();
    }
    int excl = scanv[t] - v;
    bstart[t] = excl;
    lcur[t] = excl;
    __syncthreads();

    #pragma unroll
    for (int i = 0; i < 8; ++i) {
        if (myb[i] >= 0) {
            int p = atomicAdd(&lcur[myb[i]], 1);
            s_k[p] = myk[i];
            s_y[p] = myy[i];
        }
    }
    __syncthreads();

    if (v > 0) gbase[t] = atomicAdd(&gBucketCnt[t], v);
    __syncthreads();

    for (int p = t; p < cnt; p += 256) {
        int k = s_k[p];
        int b = k >> 12;
        int gp = gbase[b] + (p - bstart[b]);
        if (gp < CAP)
            bucket_buf[(size_t)b * CAP + gp] = make_int2(k, s_y[p]);
    }
}

// ---- build: one WG per bucket; self-computed base; LDS hist + scan;
//      coalesced rowptr/inv; LDS-cursor placement; fused kappa atomics -------

__global__ __launch_bounds__(256) void build_kernel(
    const int2* __restrict__ bucket_buf, const int* __restrict__ gBucketCnt,
    int* __restrict__ rowptr, float* __restrict__ inv,
    int* __restrict__ perm, float* __restrict__ kappa, int N)
{
    __shared__ int hist[4096];
    __shared__ int cur[4096];
    __shared__ int part[256];
    const int b = blockIdx.x;
    const int t = threadIdx.x;
    const int nb = min(gBucketCnt[b], CAP);
    const int2* rec = bucket_buf + (size_t)b * CAP;

    // bucket base = exclusive prefix of gBucketCnt over buckets
    int bc = gBucketCnt[t];
    part[t] = bc;
    __syncthreads();
    for (int off = 1; off < 256; off <<= 1) {
        int u = (t >= off) ? part[t - off] : 0;
        __syncthreads();
        part[t] += u;
        __syncthreads();
    }
    __shared__ int baseS;
    if (t == b) baseS = part[t] - bc;
    __syncthreads();
    const int base = baseS;

    for (int i = t; i < 4096; i += 256) hist[i] = 0;
    __syncthreads();
    for (int j = t; j < nb; j += 256) atomicAdd(&hist[rec[j].x & 4095], 1);
    __syncthreads();

    const int i0 = t * 16;
    int s = 0;
    #pragma unroll
    for (int k = 0; k < 16; ++k) s += hist[i0 + k];
    part[t] = s;
    __syncthreads();
    for (int off = 1; off < 256; off <<= 1) {
        int u = (t >= off) ? part[t - off] : 0;
        __syncthreads();
        part[t] += u;
        __syncthreads();
    }
    int run = base + part[t] - s;
    #pragma unroll
    for (int k = 0; k < 16; ++k) {
        int c = hist[i0 + k];
        cur[i0 + k] = run;
        rowptr[b * 4096 + i0 + k] = run;
        inv[b * 4096 + i0 + k] = 1.0f / (float)max(c, 1);
        run += c;
    }
    __syncthreads();

    for (int j = t; j < nb; j += 256) {
        int k = rec[j].x, y = rec[j].y;
        int lk = k & 4095;
        int pos = atomicAdd(&cur[lk], 1);      // LDS cursor
        int sr = y & 0x1FFFF;
        int r = y >> 17;
        perm[pos] = sr;
        unsafeAtomicAdd(&kappa[(sr << 3) | r], 1.0f / (float)max(hist[lk], 1));
    }
}

// ---- fused layer 1 ----------------------------------------------------------
// one wave per 16-node tile. Per rel r: lane sg walks segments of nodes sg and
// sg+8 as two interleaved chains, each with DEPTH-2 row prefetch (rows j and
// j+1 in flight; branchless masked accumulate). Packs bf16 A-rows to LDS,
// then 16x16x32 bf16 MFMA vs pre-swizzled W frags.

__global__ __launch_bounds__(256) void rgcn1_fused_kernel(
    const int* __restrict__ rowptr, const int* __restrict__ perm,
    const float* __restrict__ inv, const ushort* __restrict__ xbf,
    const ushort* __restrict__ wfrag, const float* __restrict__ b1,
    float* __restrict__ h, int N)
{
    __shared__ ushort Abuf[4][16 * 72];   // 16x64 bf16 A-tile, row stride 72
    __shared__ int    rpS[4][144];        // rowptr[r*N+base+mm], i = r*17+mm
    __shared__ float  invS[4][128];       // inv[r*N+base+m],     i = r*16+m
    const int widx = threadIdx.x >> 6;
    const int lane = threadIdx.x & 63;
    const int wid = (blockIdx.x << 2) | widx;
    const int base = wid << 4;
    if (base >= N) return;

    const int m0 = lane & 15;
    const int q  = lane >> 4;
    const int sg = lane >> 3;
    const int cg = lane & 7;
    ushort* ab = Abuf[widx];
    int*    rpL = rpS[widx];
    float*  ivL = invS[widx];

    for (int i = lane; i < 136; i += 64) {
        int r = i / 17, mm = i - r * 17;
        rpL[i] = rowptr[(size_t)r * N + base + mm];
    }
    for (int i = lane; i < 128; i += 64)
        ivL[i] = inv[(size_t)(i >> 4) * N + base + (i & 15)];

    f32x4 acc4[4];
    #pragma unroll
    for (int ct = 0; ct < 4; ++ct) acc4[ct] = (f32x4)(0.0f);

    for (int r = 0; r < 8; ++r) {
        const int iA = r * 17 + sg;
        const int iB = iA + 8;
        int jA = rpL[iA], eA = rpL[iA + 1];
        int jB = rpL[iB], eB = rpL[iB + 1];
        float a[8] = {}, bacc[8] = {};
        int s0A = perm[(jA     < eA) ? jA     : 0];
        int s1A = perm[(jA + 1 < eA) ? jA + 1 : 0];
        int s0B = perm[(jB     < eB) ? jB     : 0];
        int s1B = perm[(jB + 1 < eB) ? jB + 1 : 0];
        while (jA < eA || jB < eB) {
            short8 r0A = *(const short8*)&xbf[(size_t)s0A * CH + (cg << 3)];
            short8 r1A = *(const short8*)&xbf[(size_t)s1A * CH + (cg << 3)];
            short8 r0B = *(const short8*)&xbf[(size_t)s0B * CH + (cg << 3)];
            short8 r1B = *(const short8*)&xbf[(size_t)s1B * CH + (cg << 3)];
            int t0A = perm[(jA + 2 < eA) ? jA + 2 : 0];   // prefetch next pair
            int t1A = perm[(jA + 3 < eA) ? jA + 3 : 0];
            int t0B = perm[(jB + 2 < eB) ? jB + 2 : 0];
            int t1B = perm[(jB + 3 < eB) ? jB + 3 : 0];
            float m0A = (jA     < eA) ? 1.f : 0.f;
            float m1A = (jA + 1 < eA) ? 1.f : 0.f;
            float m0B = (jB     < eB) ? 1.f : 0.f;
            float m1B = (jB + 1 < eB) ? 1.f : 0.f;
            #pragma unroll
            for (int k = 0; k < 8; ++k) {
                a[k]    += m0A * bf2f((ushort)r0A[k]) + m1A * bf2f((ushort)r1A[k]);
                bacc[k] += m0B * bf2f((ushort)r0B[k]) + m1B * bf2f((ushort)r1B[k]);
            }
            s0A = t0A; s1A = t1A; s0B = t0B; s1B = t1B;
            jA += 2; jB += 2;
        }
        const float ivA = ivL[(r << 4) | sg];
        const float ivB = ivL[(r << 4) | (8 + sg)];
        short8 oA, oB;
        #pragma unroll
        for (int k = 0; k < 8; ++k) {
            oA[k] = (short)f2bf(a[k] * ivA);
            oB[k] = (short)f2bf(bacc[k] * ivB);
        }
        *(short8*)&ab[sg * 72 + (cg << 3)]       = oA;
        *(short8*)&ab[(8 + sg) * 72 + (cg << 3)] = oB;

        // MFMA: 2 K-steps x 4 col-tiles (per-wave LDS is program-ordered)
        #pragma unroll
        for (int s = 0; s < 2; ++s) {
            short8 av = *(short8*)&ab[m0 * 72 + s * 32 + q * 8];
            #pragma unroll
            for (int ct = 0; ct < 4; ++ct) {
                short8 bv = *(const short8*)&wfrag[(((size_t)(r * 2 + s) * 4 + ct) * 64 + lane) * 8];
                acc4[ct] = __builtin_amdgcn_mfma_f32_16x16x32_bf16(av, bv, acc4[ct], 0, 0, 0);
            }
        }
    }

    {   // root: A-frag = x rows directly (rel index 8 in wfrag)
        int node = min(base + m0, N - 1);
        #pragma unroll
        for (int s = 0; s < 2; ++s) {
            short8 av = *(const short8*)&xbf[(size_t)node * CH + s * 32 + q * 8];
            #pragma unroll
            for (int ct = 0; ct < 4; ++ct) {
                short8 bv = *(const short8*)&wfrag[(((size_t)(8 * 2 + s) * 4 + ct) * 64 + lane) * 8];
                acc4[ct] = __builtin_amdgcn_mfma_f32_16x16x32_bf16(av, bv, acc4[ct], 0, 0, 0);
            }
        }
    }

    // epilogue: D[row=q*4+v][col=ct*16+m0]
    #pragma unroll
    for (int ct = 0; ct < 4; ++ct) {
        int c = ct * 16 + m0;
        float bb = b1[c];
        #pragma unroll
        for (int v = 0; v < 4; ++v) {
            int node = base + q * 4 + v;
            if (node < N)
                h[(size_t)node * CH + c] = fmaxf(acc4[ct][v] + bb, 0.f);
        }
    }
}

// ---- layer-2 collapse -------------------------------------------------------

__global__ __launch_bounds__(256) void kred_kernel(
    const float* __restrict__ h, const float* __restrict__ kappa,
    float* __restrict__ sacc, int N)
{
    const int lane = threadIdx.x & 63;
    const int w = threadIdx.x >> 6;
    int wave = (blockIdx.x << 2) | w;
    const int wstride = gridDim.x << 2;
    float racc[9] = {};
    for (int i = wave; i < N; i += wstride) {
        float hv = h[(size_t)i * CH + lane];
        #pragma unroll
        for (int r = 0; r < 8; ++r) racc[r] += hv * kappa[i * 8 + r];
        racc[8] += hv;
    }
    __shared__ float red[4][9][64];
    #pragma unroll
    for (int r = 0; r < 9; ++r) red[w][r][lane] = racc[r];
    __syncthreads();
    if (w == 0) {
        #pragma unroll
        for (int r = 0; r < 9; ++r) {
            float s4 = red[0][r][lane] + red[1][r][lane] + red[2][r][lane] + red[3][r][lane];
            unsafeAtomicAdd(&sacc[r * 64 + lane], s4);
        }
    }
}

__global__ void finalize_kernel(const float* __restrict__ sacc, const float* __restrict__ root2,
                                const float* __restrict__ W2, const float* __restrict__ b2,
                                float* __restrict__ out, float invN)
{
    __shared__ float g[16];
    int t = threadIdx.x;
    if (t < 16) {
        const float* s0 = sacc + 512;
        float acc = 0.f;
        for (int c = 0; c < 64; ++c) acc += s0[c] * root2[c * 16 + t];
        for (int r = 0; r < 8; ++r) {
            const float* sr = sacc + r * 64;
            for (int c = 0; c < 64; ++c) acc += sr[c] * W2[(r * 64 + c) * 16 + t];
        }
        g[t] = acc * invN + b2[t];
    }
    __syncthreads();
    if (t < 16) {
        float m = -1e30f;
        for (int i = 0; i < 16; ++i) m = fmaxf(m, g[i]);
        float s = 0.f;
        for (int i = 0; i < 16; ++i) s += expf(g[i] - m);
        out[t] = g[t] - (m + logf(s));
    }
}

// ---- launch -----------------------------------------------------------------

extern "C" void kernel_launch(void* const* d_in, const int* in_sizes, int n_in,
                              void* d_out, int out_size, void* d_ws, size_t ws_size,
                              hipStream_t stream)
{
    const float* x     = (const float*)d_in[0];
    const int*   eidx  = (const int*)d_in[1];
    const int*   etype = (const int*)d_in[2];
    const float* W1    = (const float*)d_in[3];
    const float* root1 = (const float*)d_in[4];
    const float* b1    = (const float*)d_in[5];
    const float* W2    = (const float*)d_in[6];
    const float* root2 = (const float*)d_in[7];
    const float* b2    = (const float*)d_in[8];
    float* out = (float*)d_out;

    const int E = in_sizes[1] / 2;
    const int N = in_sizes[0] / CH;
    const int NKEY = N * 8;
    const int NBUK = (NKEY + 4095) / 4096;         // 196 for N=100K (<=256)
    const int KSPACE = NBUK << 12;
    const int* srcI = eidx;
    const int* dstI = eidx + E;

    // workspace layout (4B units):
    // [gBucketCnt 256 | sacc 576 | kappa NKEY]   <- zeroed prefix
    // [inv KSPACE | rowptr KSPACE+16 | perm E | bucket_buf (8B-al) NBUK*CAP*2 |
    //  xbf N*CH/2 | wfrag 18432 | h N*CH]
    int* wsi = (int*)d_ws;
    int*   gBucketCnt = wsi;
    float* sacc       = (float*)(gBucketCnt + 256);
    float* kappa      = sacc + 576;
    float* inv        = kappa + NKEY;
    int*   rowptr     = (int*)(inv + KSPACE);
    int*   perm       = rowptr + KSPACE + 16;
    size_t off = (size_t)((perm + E) - wsi);
    off = (off + 1) & ~(size_t)1;                  // 8B-align
    int2*  bucket_buf = (int2*)(wsi + off);
    off += (size_t)NBUK * CAP * 2;
    off = (off + 7) & ~(size_t)7;                  // 32B-align
    ushort* xbf = (ushort*)(wsi + off);
    ushort* wfg = xbf + (size_t)N * CH;
    float*  h   = (float*)(wfg + 36864);

    hipMemsetAsync(d_ws, 0, (size_t)(256 + 576 + NKEY) * 4, stream);

    const int nBin = (E + BK_EDGES - 1) / BK_EDGES;
    const int nXbf = (N * CH / 4 + 255) / 256;
    const int nWf  = (36864 + 255) / 256;
    prep_kernel<<<nBin + nXbf + nWf, 256, 0, stream>>>(
        srcI, dstI, etype, x, W1, root1, gBucketCnt, bucket_buf, xbf, wfg,
        E, N, nBin, nXbf);

    build_kernel<<<NBUK, 256, 0, stream>>>(
        bucket_buf, gBucketCnt, rowptr, inv, perm, kappa, N);

    const int tiles = (N + 15) / 16;
    rgcn1_fused_kernel<<<(tiles + 3) / 4, 256, 0, stream>>>(
        rowptr, perm, inv, xbf, wfg, b1, h, N);

    kred_kernel<<<1024, 256, 0, stream>>>(h, kappa, sacc, N);
    finalize_kernel<<<1, 64, 0, stream>>>(sacc, root2, W2, b2, out, 1.0f / (float)N);
}

// Round 14
// 333.547 us; speedup vs baseline: 1.2526x; 1.0164x over previous
//
#include <hip/hip_runtime.h>
#include <hip/hip_bf16.h>

// RGCN 2-layer + global mean pool + log_softmax. Round 14.
// R13 (339us) + build_kernel widened to 1024 threads/block: same 196 buckets,
// 4x phase parallelism per block, per-CU thread occupancy 12.5% -> 50%.
// (R12 showed more/smaller buckets regress bin; R13 showed build is the
// low-occupancy straggler.) Everything else identical to R13.

#define CH 64
#define BK_EDGES 2048
#define CAP 12288   // per-bucket record capacity (avg ~8163, >40 sigma)

typedef __attribute__((ext_vector_type(8))) short short8;
typedef __attribute__((ext_vector_type(4))) float f32x4;

__device__ inline ushort f2bf(float f) {
    unsigned b = __float_as_uint(f);
    unsigned r = (b + 0x7FFFu + ((b >> 16) & 1u)) >> 16;
    return (ushort)r;
}
__device__ inline float bf2f(ushort u) {
    return __uint_as_float(((unsigned)u) << 16);
}

// ---- prep: bin (blocks [0,nBin)) + xbf (next nXbf) + wfrag (last) ----------

__global__ __launch_bounds__(256) void prep_kernel(
    const int* __restrict__ src, const int* __restrict__ dst,
    const int* __restrict__ etype, const float* __restrict__ x,
    const float* __restrict__ W1, const float* __restrict__ root1,
    int* __restrict__ gBucketCnt, int2* __restrict__ bucket_buf,
    ushort* __restrict__ xbf, ushort* __restrict__ wf,
    int E, int N, int nBin, int nXbf)
{
    __shared__ int s_k[BK_EDGES];
    __shared__ int s_y[BK_EDGES];
    __shared__ int hist[256], scanv[256], lcur[256], bstart[256], gbase[256];
    const int t = threadIdx.x;
    const int bid = blockIdx.x;

    if (bid >= nBin) {
        if (bid < nBin + nXbf) {          // bf16 copy of x
            int i = (bid - nBin) * 256 + t;
            if (i < N * CH / 4) {
                float4 v = ((const float4*)x)[i];
                ((ushort4*)xbf)[i] = make_ushort4(f2bf(v.x), f2bf(v.y), f2bf(v.z), f2bf(v.w));
            }
        } else {                          // weight B-fragment swizzle (9 mats)
            int idx = (bid - nBin - nXbf) * 256 + t;
            if (idx < 9 * 2 * 4 * 64 * 8) {
                int j    = idx & 7;
                int lane = (idx >> 3) & 63;
                int ct   = (idx >> 9) & 3;
                int ks   = (idx >> 11) & 1;
                int rel  = idx >> 12;
                int k = ks * 32 + (lane >> 4) * 8 + j;
                int n = ct * 16 + (lane & 15);
                float v = (rel < 8) ? W1[((size_t)rel * 64 + k) * 64 + n]
                                    : root1[(size_t)k * 64 + n];
                wf[idx] = f2bf(v);
            }
        }
        return;
    }

    // ---- bin: block-local counting sort by coarse bucket (key>>12) ----
    const int e0 = bid * BK_EDGES;
    const int cnt = min(BK_EDGES, E - e0);

    hist[t] = 0;
    __syncthreads();

    int myb[8], myk[8], myy[8];
    #pragma unroll
    for (int i = 0; i < 8; ++i) {
        int li = t + i * 256;
        if (li < cnt) {
            int e = e0 + li;
            int r = etype[e];
            int k = r * N + dst[e];
            myk[i] = k;
            myy[i] = (r << 17) | src[e];
            myb[i] = k >> 12;
            atomicAdd(&hist[myb[i]], 1);
        } else myb[i] = -1;
    }
    __syncthreads();

    int v = hist[t];
    scanv[t] = v;
    __syncthreads();
    for (int off = 1; off < 256; off <<= 1) {
        int u = (t >= off) ? scanv[t - off] : 0;
        __syncthreads();
        scanv[t] += u;
        __syncthreads();
    }
    int excl = scanv[t] - v;
    bstart[t] = excl;
    lcur[t] = excl;
    __syncthreads();

    #pragma unroll
    for (int i = 0; i < 8; ++i) {
        if (myb[i] >= 0) {
            int p = atomicAdd(&lcur[myb[i]], 1);
            s_k[p] = myk[i];
            s_y[p] = myy[i];
        }
    }
    __syncthreads();

    if (v > 0) gbase[t] = atomicAdd(&gBucketCnt[t], v);
    __syncthreads();

    for (int p = t; p < cnt; p += 256) {
        int k = s_k[p];
        int b = k >> 12;
        int gp = gbase[b] + (p - bstart[b]);
        if (gp < CAP)
            bucket_buf[(size_t)b * CAP + gp] = make_int2(k, s_y[p]);
    }
}

// ---- build: one WG (1024 threads) per bucket; self-computed base;
//      LDS hist + scan; coalesced rowptr/inv; LDS-cursor placement;
//      fused kappa atomics ---------------------------------------------------

__global__ __launch_bounds__(1024) void build_kernel(
    const int2* __restrict__ bucket_buf, const int* __restrict__ gBucketCnt,
    int* __restrict__ rowptr, float* __restrict__ inv,
    int* __restrict__ perm, float* __restrict__ kappa, int N)
{
    __shared__ int hist[4096];
    __shared__ int cur[4096];
    __shared__ int part[1024];
    const int b = blockIdx.x;
    const int t = threadIdx.x;
    const int nb = min(gBucketCnt[b], CAP);
    const int2* rec = bucket_buf + (size_t)b * CAP;

    // bucket base = exclusive prefix of gBucketCnt (256 entries, zero-padded)
    int bc = (t < 256) ? gBucketCnt[t] : 0;
    part[t] = bc;
    __syncthreads();
    for (int off = 1; off < 1024; off <<= 1) {
        int u = (t >= off) ? part[t - off] : 0;
        __syncthreads();
        part[t] += u;
        __syncthreads();
    }
    __shared__ int baseS;
    if (t == b) baseS = part[t] - bc;
    __syncthreads();
    const int base = baseS;

    for (int i = t; i < 4096; i += 1024) hist[i] = 0;
    __syncthreads();
    for (int j = t; j < nb; j += 1024) atomicAdd(&hist[rec[j].x & 4095], 1);
    __syncthreads();

    const int i0 = t * 4;
    int h0 = hist[i0], h1 = hist[i0 + 1], h2 = hist[i0 + 2], h3 = hist[i0 + 3];
    int s = h0 + h1 + h2 + h3;
    part[t] = s;
    __syncthreads();
    for (int off = 1; off < 1024; off <<= 1) {
        int u = (t >= off) ? part[t - off] : 0;
        __syncthreads();
        part[t] += u;
        __syncthreads();
    }
    int run = base + part[t] - s;
    int hk[4] = {h0, h1, h2, h3};
    #pragma unroll
    for (int k = 0; k < 4; ++k) {
        cur[i0 + k] = run;
        rowptr[b * 4096 + i0 + k] = run;
        inv[b * 4096 + i0 + k] = 1.0f / (float)max(hk[k], 1);
        run += hk[k];
    }
    __syncthreads();

    for (int j = t; j < nb; j += 1024) {
        int k = rec[j].x, y = rec[j].y;
        int lk = k & 4095;
        int pos = atomicAdd(&cur[lk], 1);      // LDS cursor
        int sr = y & 0x1FFFF;
        int r = y >> 17;
        perm[pos] = sr;
        unsafeAtomicAdd(&kappa[(sr << 3) | r], 1.0f / (float)max(hist[lk], 1));
    }
}

// ---- fused layer 1 ----------------------------------------------------------
// one wave per 16-node tile. Per rel r: lane sg walks segments of nodes sg and
// sg+8 as two interleaved chains, each with depth-2 row prefetch (rows j and
// j+1 in flight; branchless masked accumulate). Packs bf16 A-rows to LDS,
// then 16x16x32 bf16 MFMA vs pre-swizzled W frags.

__global__ __launch_bounds__(256) void rgcn1_fused_kernel(
    const int* __restrict__ rowptr, const int* __restrict__ perm,
    const float* __restrict__ inv, const ushort* __restrict__ xbf,
    const ushort* __restrict__ wfrag, const float* __restrict__ b1,
    float* __restrict__ h, int N)
{
    __shared__ ushort Abuf[4][16 * 72];   // 16x64 bf16 A-tile, row stride 72
    __shared__ int    rpS[4][144];        // rowptr[r*N+base+mm], i = r*17+mm
    __shared__ float  invS[4][128];       // inv[r*N+base+m],     i = r*16+m
    const int widx = threadIdx.x >> 6;
    const int lane = threadIdx.x & 63;
    const int wid = (blockIdx.x << 2) | widx;
    const int base = wid << 4;
    if (base >= N) return;

    const int m0 = lane & 15;
    const int q  = lane >> 4;
    const int sg = lane >> 3;
    const int cg = lane & 7;
    ushort* ab = Abuf[widx];
    int*    rpL = rpS[widx];
    float*  ivL = invS[widx];

    for (int i = lane; i < 136; i += 64) {
        int r = i / 17, mm = i - r * 17;
        rpL[i] = rowptr[(size_t)r * N + base + mm];
    }
    for (int i = lane; i < 128; i += 64)
        ivL[i] = inv[(size_t)(i >> 4) * N + base + (i & 15)];

    f32x4 acc4[4];
    #pragma unroll
    for (int ct = 0; ct < 4; ++ct) acc4[ct] = (f32x4)(0.0f);

    for (int r = 0; r < 8; ++r) {
        const int iA = r * 17 + sg;
        const int iB = iA + 8;
        int jA = rpL[iA], eA = rpL[iA + 1];
        int jB = rpL[iB], eB = rpL[iB + 1];
        float a[8] = {}, bacc[8] = {};
        int s0A = perm[(jA     < eA) ? jA     : 0];
        int s1A = perm[(jA + 1 < eA) ? jA + 1 : 0];
        int s0B = perm[(jB     < eB) ? jB     : 0];
        int s1B = perm[(jB + 1 < eB) ? jB + 1 : 0];
        while (jA < eA || jB < eB) {
            short8 r0A = *(const short8*)&xbf[(size_t)s0A * CH + (cg << 3)];
            short8 r1A = *(const short8*)&xbf[(size_t)s1A * CH + (cg << 3)];
            short8 r0B = *(const short8*)&xbf[(size_t)s0B * CH + (cg << 3)];
            short8 r1B = *(const short8*)&xbf[(size_t)s1B * CH + (cg << 3)];
            int t0A = perm[(jA + 2 < eA) ? jA + 2 : 0];   // prefetch next pair
            int t1A = perm[(jA + 3 < eA) ? jA + 3 : 0];
            int t0B = perm[(jB + 2 < eB) ? jB + 2 : 0];
            int t1B = perm[(jB + 3 < eB) ? jB + 3 : 0];
            float m0A = (jA     < eA) ? 1.f : 0.f;
            float m1A = (jA + 1 < eA) ? 1.f : 0.f;
            float m0B = (jB     < eB) ? 1.f : 0.f;
            float m1B = (jB + 1 < eB) ? 1.f : 0.f;
            #pragma unroll
            for (int k = 0; k < 8; ++k) {
                a[k]    += m0A * bf2f((ushort)r0A[k]) + m1A * bf2f((ushort)r1A[k]);
                bacc[k] += m0B * bf2f((ushort)r0B[k]) + m1B * bf2f((ushort)r1B[k]);
            }
            s0A = t0A; s1A = t1A; s0B = t0B; s1B = t1B;
            jA += 2; jB += 2;
        }
        const float ivA = ivL[(r << 4) | sg];
        const float ivB = ivL[(r << 4) | (8 + sg)];
        short8 oA, oB;
        #pragma unroll
        for (int k = 0; k < 8; ++k) {
            oA[k] = (short)f2bf(a[k] * ivA);
            oB[k] = (short)f2bf(bacc[k] * ivB);
        }
        *(short8*)&ab[sg * 72 + (cg << 3)]       = oA;
        *(short8*)&ab[(8 + sg) * 72 + (cg << 3)] = oB;

        // MFMA: 2 K-steps x 4 col-tiles (per-wave LDS is program-ordered)
        #pragma unroll
        for (int s = 0; s < 2; ++s) {
            short8 av = *(short8*)&ab[m0 * 72 + s * 32 + q * 8];
            #pragma unroll
            for (int ct = 0; ct < 4; ++ct) {
                short8 bv = *(const short8*)&wfrag[(((size_t)(r * 2 + s) * 4 + ct) * 64 + lane) * 8];
                acc4[ct] = __builtin_amdgcn_mfma_f32_16x16x32_bf16(av, bv, acc4[ct], 0, 0, 0);
            }
        }
    }

    {   // root: A-frag = x rows directly (rel index 8 in wfrag)
        int node = min(base + m0, N - 1);
        #pragma unroll
        for (int s = 0; s < 2; ++s) {
            short8 av = *(const short8*)&xbf[(size_t)node * CH + s * 32 + q * 8];
            #pragma unroll
            for (int ct = 0; ct < 4; ++ct) {
                short8 bv = *(const short8*)&wfrag[(((size_t)(8 * 2 + s) * 4 + ct) * 64 + lane) * 8];
                acc4[ct] = __builtin_amdgcn_mfma_f32_16x16x32_bf16(av, bv, acc4[ct], 0, 0, 0);
            }
        }
    }

    // epilogue: D[row=q*4+v][col=ct*16+m0]
    #pragma unroll
    for (int ct = 0; ct < 4; ++ct) {
        int c = ct * 16 + m0;
        float bb = b1[c];
        #pragma unroll
        for (int v = 0; v < 4; ++v) {
            int node = base + q * 4 + v;
            if (node < N)
                h[(size_t)node * CH + c] = fmaxf(acc4[ct][v] + bb, 0.f);
        }
    }
}

// ---- layer-2 collapse -------------------------------------------------------

__global__ __launch_bounds__(256) void kred_kernel(
    const float* __restrict__ h, const float* __restrict__ kappa,
    float* __restrict__ sacc, int N)
{
    const int lane = threadIdx.x & 63;
    const int w = threadIdx.x >> 6;
    int wave = (blockIdx.x << 2) | w;
    const int wstride = gridDim.x << 2;
    float racc[9] = {};
    for (int i = wave; i < N; i += wstride) {
        float hv = h[(size_t)i * CH + lane];
        #pragma unroll
        for (int r = 0; r < 8; ++r) racc[r] += hv * kappa[i * 8 + r];
        racc[8] += hv;
    }
    __shared__ float red[4][9][64];
    #pragma unroll
    for (int r = 0; r < 9; ++r) red[w][r][lane] = racc[r];
    __syncthreads();
    if (w == 0) {
        #pragma unroll
        for (int r = 0; r < 9; ++r) {
            float s4 = red[0][r][lane] + red[1][r][lane] + red[2][r][lane] + red[3][r][lane];
            unsafeAtomicAdd(&sacc[r * 64 + lane], s4);
        }
    }
}

__global__ void finalize_kernel(const float* __restrict__ sacc, const float* __restrict__ root2,
                                const float* __restrict__ W2, const float* __restrict__ b2,
                                float* __restrict__ out, float invN)
{
    __shared__ float g[16];
    int t = threadIdx.x;
    if (t < 16) {
        const float* s0 = sacc + 512;
        float acc = 0.f;
        for (int c = 0; c < 64; ++c) acc += s0[c] * root2[c * 16 + t];
        for (int r = 0; r < 8; ++r) {
            const float* sr = sacc + r * 64;
            for (int c = 0; c < 64; ++c) acc += sr[c] * W2[(r * 64 + c) * 16 + t];
        }
        g[t] = acc * invN + b2[t];
    }
    __syncthreads();
    if (t < 16) {
        float m = -1e30f;
        for (int i = 0; i < 16; ++i) m = fmaxf(m, g[i]);
        float s = 0.f;
        for (int i = 0; i < 16; ++i) s += expf(g[i] - m);
        out[t] = g[t] - (m + logf(s));
    }
}

// ---- launch -----------------------------------------------------------------

extern "C" void kernel_launch(void* const* d_in, const int* in_sizes, int n_in,
                              void* d_out, int out_size, void* d_ws, size_t ws_size,
                              hipStream_t stream)
{
    const float* x     = (const float*)d_in[0];
    const int*   eidx  = (const int*)d_in[1];
    const int*   etype = (const int*)d_in[2];
    const float* W1    = (const float*)d_in[3];
    const float* root1 = (const float*)d_in[4];
    const float* b1    = (const float*)d_in[5];
    const float* W2    = (const float*)d_in[6];
    const float* root2 = (const float*)d_in[7];
    const float* b2    = (const float*)d_in[8];
    float* out = (float*)d_out;

    const int E = in_sizes[1] / 2;
    const int N = in_sizes[0] / CH;
    const int NKEY = N * 8;
    const int NBUK = (NKEY + 4095) / 4096;         // 196 for N=100K (<=256)
    const int KSPACE = NBUK << 12;
    const int* srcI = eidx;
    const int* dstI = eidx + E;

    // workspace layout (4B units):
    // [gBucketCnt 256 | sacc 576 | kappa NKEY]   <- zeroed prefix
    // [inv KSPACE | rowptr KSPACE+16 | perm E | bucket_buf (8B-al) NBUK*CAP*2 |
    //  xbf N*CH/2 | wfrag 18432 | h N*CH]
    int* wsi = (int*)d_ws;
    int*   gBucketCnt = wsi;
    float* sacc       = (float*)(gBucketCnt + 256);
    float* kappa      = sacc + 576;
    float* inv        = kappa + NKEY;
    int*   rowptr     = (int*)(inv + KSPACE);
    int*   perm       = rowptr + KSPACE + 16;
    size_t off = (size_t)((perm + E) - wsi);
    off = (off + 1) & ~(size_t)1;                  // 8B-align
    int2*  bucket_buf = (int2*)(wsi + off);
    off += (size_t)NBUK * CAP * 2;
    off = (off + 7) & ~(size_t)7;                  // 32B-align
    ushort* xbf = (ushort*)(wsi + off);
    ushort* wfg = xbf + (size_t)N * CH;
    float*  h   = (float*)(wfg + 36864);

    hipMemsetAsync(d_ws, 0, (size_t)(256 + 576 + NKEY) * 4, stream);

    const int nBin = (E + BK_EDGES - 1) / BK_EDGES;
    const int nXbf = (N * CH / 4 + 255) / 256;
    const int nWf  = (36864 + 255) / 256;
    prep_kernel<<<nBin + nXbf + nWf, 256, 0, stream>>>(
        srcI, dstI, etype, x, W1, root1, gBucketCnt, bucket_buf, xbf, wfg,
        E, N, nBin, nXbf);

    build_kernel<<<NBUK, 1024, 0, stream>>>(
        bucket_buf, gBucketCnt, rowptr, inv, perm, kappa, N);

    const int tiles = (N + 15) / 16;
    rgcn1_fused_kernel<<<(tiles + 3) / 4, 256, 0, stream>>>(
        rowptr, perm, inv, xbf, wfg, b1, h, N);

    kred_kernel<<<1024, 256, 0, stream>>>(h, kappa, sacc, N);
    finalize_kernel<<<1, 64, 0, stream>>>(sacc, root2, W2, b2, out, 1.0f / (float)N);
}